// Round 16
// baseline (630.214 us; speedup 1.0000x reference)
//
#include <hip/hip_runtime.h>
#include <math.h>

#define HWs (512*512)

typedef short  s8v __attribute__((ext_vector_type(8)));   // 8 bf16 (4 VGPRs)
typedef short  s4v __attribute__((ext_vector_type(4)));   // 4 bf16 (2 VGPRs)
typedef float  f4v __attribute__((ext_vector_type(4)));   // MFMA acc

__device__ __forceinline__ float lo16(unsigned int u){ union{unsigned int i; float f;} z; z.i=u<<16;         return z.f; }
__device__ __forceinline__ float hi16(unsigned int u){ union{unsigned int i; float f;} z; z.i=u&0xffff0000u; return z.f; }
__device__ __forceinline__ unsigned int cvtpk(float lo, float hi){
  unsigned int r; asm("v_cvt_pk_bf16_f32 %0, %1, %2" : "=v"(r) : "v"(lo), "v"(hi)); return r;
}
__device__ __forceinline__ unsigned short f2bf_rne(float f){
  union{float g; unsigned int u;} a; a.g=f;
  unsigned int r = a.u + 0x7fffu + ((a.u>>16)&1u);
  return (unsigned short)(r>>16);
}
// short-family LDS stores (TBAA-compatible with s8v loads)
__device__ __forceinline__ void st8(void* p, unsigned int a, unsigned int b){
  union{ unsigned int u[2]; s4v v; } z; z.u[0]=a; z.u[1]=b;
  *(s4v*)p = z.v;
}
__device__ __forceinline__ void st16(void* p, unsigned int a, unsigned int b, unsigned int c, unsigned int d){
  union{ unsigned int u[4]; s8v v; } z; z.u[0]=a; z.u[1]=b; z.u[2]=c; z.u[3]=d;
  *(s8v*)p = z.v;
}

// XOR swizzle on 16B units within a 128B row
#define SWZ(row) (((((row)&7) ^ (((row)>>3)&7)))<<4)

// ---------------- setup kernels ----------------
__global__ void conv_wb(const float* __restrict__ inw, const float* __restrict__ w1,
                        const float* __restrict__ w2, unsigned short* __restrict__ ws){
  int i = blockIdx.x*256 + threadIdx.x;
  if (i < 12288)      ws[i] = f2bf_rne(inw[i]);
  else if (i < 20480) ws[i] = f2bf_rne(w1[i-12288]);
  else                ws[i] = f2bf_rne(w2[i-20480]);
}

__global__ void fuse_proj_kernel(const float* __restrict__ out_w, const float* __restrict__ out_b,
                                 const float* __restrict__ proj_w, const float* __restrict__ proj_b,
                                 unsigned short* __restrict__ wf_bf, float* __restrict__ bfv){
  int i = blockIdx.x*256 + threadIdx.x;
  if (i >= 64*64) return;
  int c = i>>6, k = i&63;
  float acc = 0.f;
  for (int m=0;m<64;m++) acc += proj_w[c*64+m]*out_w[m*64+k];
  wf_bf[i] = f2bf_rne(acc);
  if (k==0){
    float ab = proj_b[c];
    for (int m=0;m<64;m++) ab += proj_w[c*64+m]*out_b[m];
    bfv[c] = ab;
  }
}

// ---------------- main: 512 threads = 8 waves; 2 windows; 4 waves per window ----------------
// Per-window 32KB: RA tn->P->tn2->mlp2out ; RB q->o->h[0:64] ; RC k->projout ; RD V^T->h[64:128]
// Thread map: pc=t&15, pr=(t>>4)&7, cb=t>>7 ; win=(pc>>3)&1, tok=pr*8+(pc&7)
// Wave map: wave w: window=w&1, tm=w>>1 (token rows 16tm..16tm+15)
// GEMM rule: mfma(X, Y): lane (g,c) reg r = dot(Xrow[4g+r], Yrow[c]); frags = elems 8g..8g+7 (+32*kk)
// XCD swizzle: bijective remap n = (bid&7)*1024 + bid>>3 — verified: FETCH_SIZE halved (R11).
// LN partials layout: [cb][tok] (cb*512 + tok*8) — bank (tok*2)%32 spans 16 banks => ~4-way
// (was tok*32+cb*8: 4 banks => ~16-way, the dominant SQ_LDS_BANK_CONFLICT source).
// NOTE: phase-2 h-loop MUST stay "#pragma unroll 1" with the fences exactly as-is — full unroll
// breaks the P-write->pa-read LDS alias ordering (R10 NaN). Thread-map/barrier perturbations
// are schedule-fragile (R13/R14) — partials change here is barrier-separated (alias-free).
__global__ __launch_bounds__(512,4) void hat_main(
    const float* __restrict__ x,
    const float* __restrict__ n1g, const float* __restrict__ n1b,
    const float* __restrict__ inb,
    const unsigned short* __restrict__ wbf,
    const float* __restrict__ bfv,
    const float* __restrict__ n2g, const float* __restrict__ n2b,
    const float* __restrict__ b1, const float* __restrict__ b2,
    float* __restrict__ out)
{
  __shared__ __align__(16) unsigned char lds[65536];
  #define RA 0
  #define RB 8192
  #define RC 16384
  #define RD 24576

  const int t = threadIdx.x;
  const int l = t & 63;
  const int g = (l>>4)&3, c = l&15;
  const int w  = t>>6;                  // 0..7
  const int tm = w>>1;
  const int wb = (w&1)<<15;
  const int cb = t>>7;                  // 0..3 (16 channels each)
  const int pr = (t>>4)&7;
  const int pc = t&15;
  const int tok = pr*8 + (pc&7);
  const int wtb = ((pc>>3)&1)<<15;

  const int n = ((blockIdx.x & 7) << 10) | (blockIdx.x >> 3);   // XCD-chunked bijective remap
  const int ww2 = n&31, wh=(n>>5)&63, b=n>>11;
  const size_t pix = (size_t)(wh*8+pr)*512 + ww2*16 + pc;
  const float* xp = x + ((size_t)b*64 + 16*cb)*HWs + pix;

  const unsigned short* inw_bf = wbf;
  const unsigned short* w1_bf  = wbf + 12288;
  const unsigned short* w2_bf  = wbf + 20480;
  const unsigned short* wf_bf  = wbf + 28672;

  // ---------- phase 0a: coalesced load of 16 channels, LN1 partials ----------
  float xr[16];
  #pragma unroll
  for (int i=0;i<16;i++) xr[i] = xp[(size_t)i*HWs];
  {
    float s1=0.f, s2=0.f;
    #pragma unroll
    for (int i=0;i<16;i++){ s1 += xr[i]; s2 += xr[i]*xr[i]; }
    *(float2*)(lds + wtb + RD + cb*512 + tok*8) = make_float2(s1, s2);
  }
  __syncthreads();   // b1

  // ---------- phase 0b: LN1 normalize, stage tn ----------
  unsigned int xres[8];
  {
    float S=0.f, SS=0.f;
    #pragma unroll
    for (int grp=0; grp<4; grp++){
      float2 p = *(const float2*)(lds + wtb + RD + grp*512 + tok*8);
      S += p.x; SS += p.y;
    }
    float mu = S*(1.f/64.f);
    float var = SS*(1.f/64.f) - mu*mu;
    float rstd = rsqrtf(var + 1e-5f);
    float tv[16];
    #pragma unroll
    for (int i=0;i<16;i++) tv[i] = (xr[i]-mu)*rstd*n1g[16*cb+i] + n1b[16*cb+i];
    #pragma unroll
    for (int j=0;j<8;j++) xres[j] = cvtpk(xr[2*j], xr[2*j+1]);
    int sw = SWZ(tok);
    st16(lds + wtb + RA + tok*128 + ((32*cb   ) ^ sw),
         cvtpk(tv[0],tv[1]), cvtpk(tv[2],tv[3]), cvtpk(tv[4],tv[5]), cvtpk(tv[6],tv[7]));
    st16(lds + wtb + RA + tok*128 + ((32*cb+16) ^ sw),
         cvtpk(tv[8],tv[9]), cvtpk(tv[10],tv[11]), cvtpk(tv[12],tv[13]), cvtpk(tv[14],tv[15]));
  }
  __syncthreads();   // b2

  const int row_a = 16*tm + c;
  const int swa = SWZ(row_a);
  const float scale = 0.17677669529663688f; // 1/sqrt(32)

  // ---------- phase 1: QKV ----------
  s8v a0 = *(const s8v*)(lds + wb + RA + row_a*128 + ((16*g   ) ^ swa));
  s8v a1 = *(const s8v*)(lds + wb + RA + row_a*128 + ((64+16*g) ^ swa));
  #pragma unroll 1
  for (int chunk=0; chunk<2; chunk++){
    f4v acc[4] = {};
    #pragma unroll
    for (int tn=0;tn<4;tn++){
      s8v wf0 = *(const s8v*)(inw_bf + (64*chunk+16*tn+c)*64 + 8*g);
      s8v wf1 = *(const s8v*)(inw_bf + (64*chunk+16*tn+c)*64 + 32 + 8*g);
      acc[tn] = __builtin_amdgcn_mfma_f32_16x16x32_bf16(wf0, a0, acc[tn], 0,0,0);
      acc[tn] = __builtin_amdgcn_mfma_f32_16x16x32_bf16(wf1, a1, acc[tn], 0,0,0);
    }
    const int reg = (chunk==0) ? RB : RC;
    #pragma unroll
    for (int tn=0;tn<4;tn++){
      float4 b4 = *(const float4*)(inb + 64*chunk + 16*tn + 4*g);
      float v0=acc[tn][0]+b4.x, v1=acc[tn][1]+b4.y, v2=acc[tn][2]+b4.z, v3=acc[tn][3]+b4.w;
      if (chunk==0){ v0*=scale; v1*=scale; v2*=scale; v3*=scale; }
      st8(lds + wb + reg + row_a*128 + ((2*(16*tn+4*g)) ^ swa), cvtpk(v0,v1), cvtpk(v2,v3));
    }
  }
  { // V chunk (unflipped) -> transposed packed write to RD (V^T[d][tok])
    f4v acc[4] = {};
    #pragma unroll
    for (int tn=0;tn<4;tn++){
      s8v wf0 = *(const s8v*)(inw_bf + (128+16*tn+c)*64 + 8*g);
      s8v wf1 = *(const s8v*)(inw_bf + (128+16*tn+c)*64 + 32 + 8*g);
      acc[tn] = __builtin_amdgcn_mfma_f32_16x16x32_bf16(a0, wf0, acc[tn], 0,0,0);
      acc[tn] = __builtin_amdgcn_mfma_f32_16x16x32_bf16(a1, wf1, acc[tn], 0,0,0);
    }
    #pragma unroll
    for (int tn=0;tn<4;tn++){
      int drow = 16*tn + c;
      float bias = inb[128 + drow];
      st8(lds + wb + RD + drow*128 + ((2*(16*tm+4*g)) ^ SWZ(drow)),
          cvtpk(acc[tn][0]+bias, acc[tn][1]+bias), cvtpk(acc[tn][2]+bias, acc[tn][3]+bias));
    }
  }
  __syncthreads();   // b3

  // ---------- phase 2: attention ----------
  #pragma unroll 1
  for (int h=0; h<2; h++){
    s8v qa = *(const s8v*)(lds + wb + RB + row_a*128 + ((64*h+16*g) ^ swa));
    f4v sacc[4] = {};
    #pragma unroll
    for (int tn=0;tn<4;tn++){
      int kr = 16*tn + c;
      s8v kb = *(const s8v*)(lds + wb + RC + kr*128 + ((64*h+16*g) ^ SWZ(kr)));
      sacc[tn] = __builtin_amdgcn_mfma_f32_16x16x32_bf16(kb, qa, sacc[tn], 0,0,0);
    }
    // lane (g,c): sacc[tn][r] = S[ktok=16tn+4g+r][qtok=16tm+c]
    // softmax over ktok: in-lane tree(16) + shfl over g (16,32)
    float mt[4];
    #pragma unroll
    for (int tn=0;tn<4;tn++)
      mt[tn] = fmaxf(fmaxf(sacc[tn][0],sacc[tn][1]), fmaxf(sacc[tn][2],sacc[tn][3]));
    float m = fmaxf(fmaxf(mt[0],mt[1]), fmaxf(mt[2],mt[3]));
    m = fmaxf(m, __shfl_xor(m, 16));
    m = fmaxf(m, __shfl_xor(m, 32));
    float lsum = 0.f;
    float p[4][4];
    #pragma unroll
    for (int tn=0;tn<4;tn++)
      #pragma unroll
      for (int rr=0;rr<4;rr++){ float e = __expf(sacc[tn][rr]-m); p[tn][rr]=e; lsum+=e; }
    lsum += __shfl_xor(lsum, 16);
    lsum += __shfl_xor(lsum, 32);
    float inv = 1.f/lsum;
    // P[qtok][ktok] packed write (own row)
    #pragma unroll
    for (int tn=0;tn<4;tn++)
      st8(lds + wb + RA + row_a*128 + ((2*(16*tn+4*g)) ^ swa),
          cvtpk(p[tn][0]*inv, p[tn][1]*inv), cvtpk(p[tn][2]*inv, p[tn][3]*inv));
    asm volatile("" ::: "memory");   // order P writes before pa reads (same-wave RAW)
    s8v pa0 = *(const s8v*)(lds + wb + RA + row_a*128 + ((16*g   ) ^ swa));
    s8v pa1 = *(const s8v*)(lds + wb + RA + row_a*128 + ((64+16*g) ^ swa));
    #pragma unroll
    for (int tnl=0; tnl<2; tnl++){
      int vr = 32*h + 16*tnl + c;
      int svr = SWZ(vr);
      s8v vb0 = *(const s8v*)(lds + wb + RD + vr*128 + ((16*g   ) ^ svr));
      s8v vb1 = *(const s8v*)(lds + wb + RD + vr*128 + ((64+16*g) ^ svr));
      f4v oc = {};
      oc = __builtin_amdgcn_mfma_f32_16x16x32_bf16(vb0, pa0, oc, 0,0,0);
      oc = __builtin_amdgcn_mfma_f32_16x16x32_bf16(vb1, pa1, oc, 0,0,0);
      st8(lds + wb + RB + row_a*128 + ((64*h + 32*tnl + 8*g) ^ swa),
          cvtpk(oc[0], oc[1]), cvtpk(oc[2], oc[3]));
    }
  }
  __syncthreads();   // b4 (all RC/RD reads done before proj overwrites RC)

  // ---------- phase 3: fused proj -> RC ----------
  {
    s8v oa0 = *(const s8v*)(lds + wb + RB + row_a*128 + ((16*g   ) ^ swa));
    s8v oa1 = *(const s8v*)(lds + wb + RB + row_a*128 + ((64+16*g) ^ swa));
    f4v acc[4] = {};
    #pragma unroll
    for (int tn=0;tn<4;tn++){
      s8v wf0 = *(const s8v*)(wf_bf + (16*tn+c)*64 + 8*g);
      s8v wf1 = *(const s8v*)(wf_bf + (16*tn+c)*64 + 32 + 8*g);
      acc[tn] = __builtin_amdgcn_mfma_f32_16x16x32_bf16(wf0, oa0, acc[tn], 0,0,0);
      acc[tn] = __builtin_amdgcn_mfma_f32_16x16x32_bf16(wf1, oa1, acc[tn], 0,0,0);
    }
    #pragma unroll
    for (int tn=0;tn<4;tn++){
      float4 b4 = *(const float4*)(bfv + 16*tn + 4*g);
      st8(lds + wb + RC + row_a*128 + ((2*(16*tn+4*g)) ^ swa),
          cvtpk(acc[tn][0]+b4.x, acc[tn][1]+b4.y), cvtpk(acc[tn][2]+b4.z, acc[tn][3]+b4.w));
    }
  }
  __syncthreads();   // b5 (-> thread map)

  // ---------- phase 4: residual + LN2 (thread map) ----------
  float row2[16];
  {
    int sw = SWZ(tok);
    uint4 A0 = *(const uint4*)(lds + wtb + RC + tok*128 + ((32*cb   ) ^ sw));
    uint4 A1 = *(const uint4*)(lds + wtb + RC + tok*128 + ((32*cb+16) ^ sw));
    unsigned int pr8[8] = {A0.x,A0.y,A0.z,A0.w,A1.x,A1.y,A1.z,A1.w};
    #pragma unroll
    for (int j=0;j<8;j++){
      row2[2*j]   = lo16(pr8[j]) + lo16(xres[j]);
      row2[2*j+1] = hi16(pr8[j]) + hi16(xres[j]);
    }
    float s1=0.f, s2=0.f;
    #pragma unroll
    for (int i=0;i<16;i++){ s1 += row2[i]; s2 += row2[i]*row2[i]; }
    *(float2*)(lds + wtb + RB + cb*512 + tok*8) = make_float2(s1, s2);
  }
  __syncthreads();   // b6
  {
    float S=0.f, SS=0.f;
    #pragma unroll
    for (int grp=0; grp<4; grp++){
      float2 p = *(const float2*)(lds + wtb + RB + grp*512 + tok*8);
      S += p.x; SS += p.y;
    }
    float mu2 = S*(1.f/64.f);
    float v2 = SS*(1.f/64.f) - mu2*mu2;
    float rstd2 = rsqrtf(v2 + 1e-5f);
    float tv[16];
    #pragma unroll
    for (int i=0;i<16;i++) tv[i] = (row2[i]-mu2)*rstd2*n2g[16*cb+i] + n2b[16*cb+i];
    int sw = SWZ(tok);
    st16(lds + wtb + RA + tok*128 + ((32*cb   ) ^ sw),
         cvtpk(tv[0],tv[1]), cvtpk(tv[2],tv[3]), cvtpk(tv[4],tv[5]), cvtpk(tv[6],tv[7]));
    st16(lds + wtb + RA + tok*128 + ((32*cb+16) ^ sw),
         cvtpk(tv[8],tv[9]), cvtpk(tv[10],tv[11]), cvtpk(tv[12],tv[13]), cvtpk(tv[14],tv[15]));
  }
  __syncthreads();   // b7 (-> wave map)

  // ---------- phase 5: MLP1 + gelu -> RB (h0), RD (h1) ----------
  {
    s8v la0 = *(const s8v*)(lds + wb + RA + row_a*128 + ((16*g   ) ^ swa));
    s8v la1 = *(const s8v*)(lds + wb + RA + row_a*128 + ((64+16*g) ^ swa));
    #pragma unroll 1
    for (int nch=0; nch<2; nch++){
      f4v acc[4] = {};
      #pragma unroll
      for (int tn=0;tn<4;tn++){
        s8v wf0 = *(const s8v*)(w1_bf + (64*nch+16*tn+c)*64 + 8*g);
        s8v wf1 = *(const s8v*)(w1_bf + (64*nch+16*tn+c)*64 + 32 + 8*g);
        acc[tn] = __builtin_amdgcn_mfma_f32_16x16x32_bf16(wf0, la0, acc[tn], 0,0,0);
        acc[tn] = __builtin_amdgcn_mfma_f32_16x16x32_bf16(wf1, la1, acc[tn], 0,0,0);
      }
      const int reg = nch ? RD : RB;
      #pragma unroll
      for (int tn=0;tn<4;tn++){
        float4 b4 = *(const float4*)(b1 + 64*nch + 16*tn + 4*g);
        float vv[4] = {acc[tn][0]+b4.x, acc[tn][1]+b4.y, acc[tn][2]+b4.z, acc[tn][3]+b4.w};
        #pragma unroll
        for (int rr=0;rr<4;rr++){
          float v = vv[rr];
          float z = v*(1.595769122f + 0.071354816f*v*v);
          vv[rr] = v/(1.f + __expf(-z));
        }
        st8(lds + wb + reg + row_a*128 + ((2*(16*tn+4*g)) ^ swa), cvtpk(vv[0],vv[1]), cvtpk(vv[2],vv[3]));
      }
    }
  }
  asm volatile("" ::: "memory");   // order MLP1 h-writes before MLP2 ha reads (same-wave RAW)
  // ---------- phase 6: MLP2 -> RA (own rows; no barrier needed) ----------
  {
    f4v acc[4] = {};
    #pragma unroll
    for (int kk=0;kk<4;kk++){
      const int reg = (kk<2) ? RB : RD;
      s8v ha = *(const s8v*)(lds + wb + reg + row_a*128 + ((64*(kk&1)+16*g) ^ swa));
      #pragma unroll
      for (int tn=0;tn<4;tn++){
        s8v wf = *(const s8v*)(w2_bf + (16*tn+c)*128 + 32*kk + 8*g);
        acc[tn] = __builtin_amdgcn_mfma_f32_16x16x32_bf16(wf, ha, acc[tn], 0,0,0);
      }
    }
    #pragma unroll
    for (int tn=0;tn<4;tn++){
      float4 b4 = *(const float4*)(b2 + 16*tn + 4*g);
      st8(lds + wb + RA + row_a*128 + ((2*(16*tn+4*g)) ^ swa),
          cvtpk(acc[tn][0]+b4.x, acc[tn][1]+b4.y), cvtpk(acc[tn][2]+b4.z, acc[tn][3]+b4.w));
    }
  }
  __syncthreads();   // b8 (-> thread map)

  // ---------- epilogue: + residual (row2 regs), coalesced store ----------
  {
    int sw = SWZ(tok);
    uint4 A0 = *(const uint4*)(lds + wtb + RA + tok*128 + ((32*cb   ) ^ sw));
    uint4 A1 = *(const uint4*)(lds + wtb + RA + tok*128 + ((32*cb+16) ^ sw));
    unsigned int pr8[8] = {A0.x,A0.y,A0.z,A0.w,A1.x,A1.y,A1.z,A1.w};
    float* op = out + ((size_t)b*64 + 16*cb)*HWs + pix;
    #pragma unroll
    for (int j=0;j<8;j++){
      op[(size_t)(2*j  )*HWs] = lo16(pr8[j]) + row2[2*j];
      op[(size_t)(2*j+1)*HWs] = hi16(pr8[j]) + row2[2*j+1];
    }
  }
}

extern "C" void kernel_launch(void* const* d_in, const int* in_sizes, int n_in,
                              void* d_out, int out_size, void* d_ws, size_t ws_size,
                              hipStream_t stream) {
  const float* x    = (const float*)d_in[0];
  const float* n1g  = (const float*)d_in[1];
  const float* n1b  = (const float*)d_in[2];
  const float* inw  = (const float*)d_in[3];
  const float* inb  = (const float*)d_in[4];
  const float* outw = (const float*)d_in[5];
  const float* outb = (const float*)d_in[6];
  const float* pw   = (const float*)d_in[7];
  const float* pb   = (const float*)d_in[8];
  const float* n2g  = (const float*)d_in[9];
  const float* n2b  = (const float*)d_in[10];
  const float* w1   = (const float*)d_in[11];
  const float* b1   = (const float*)d_in[12];
  const float* w2   = (const float*)d_in[13];
  const float* b2   = (const float*)d_in[14];

  unsigned short* wsu = (unsigned short*)d_ws;
  unsigned short* wf_bf = wsu + 28672;
  float* bfv = (float*)((char*)d_ws + 65536);

  hipLaunchKernelGGL(conv_wb, dim3(112), dim3(256), 0, stream, inw, w1, w2, wsu);
  hipLaunchKernelGGL(fuse_proj_kernel, dim3(16), dim3(256), 0, stream, outw, outb, pw, pb, wf_bf, bfv);
  hipLaunchKernelGGL(hat_main, dim3(8192), dim3(512), 0, stream,
                     x, n1g, n1b, inb, wsu, bfv, n2g, n2b, b1, b2, (float*)d_out);
}

// Round 17
// 618.635 us; speedup vs baseline: 1.0187x; 1.0187x over previous
//
#include <hip/hip_runtime.h>
#include <math.h>

#define HWs (512*512)

typedef short  s8v __attribute__((ext_vector_type(8)));   // 8 bf16 (4 VGPRs)
typedef short  s4v __attribute__((ext_vector_type(4)));   // 4 bf16 (2 VGPRs)
typedef float  f4v __attribute__((ext_vector_type(4)));   // MFMA acc

__device__ __forceinline__ float lo16(unsigned int u){ union{unsigned int i; float f;} z; z.i=u<<16;         return z.f; }
__device__ __forceinline__ float hi16(unsigned int u){ union{unsigned int i; float f;} z; z.i=u&0xffff0000u; return z.f; }
__device__ __forceinline__ unsigned int cvtpk(float lo, float hi){
  unsigned int r; asm("v_cvt_pk_bf16_f32 %0, %1, %2" : "=v"(r) : "v"(lo), "v"(hi)); return r;
}
__device__ __forceinline__ unsigned short f2bf_rne(float f){
  union{float g; unsigned int u;} a; a.g=f;
  unsigned int r = a.u + 0x7fffu + ((a.u>>16)&1u);
  return (unsigned short)(r>>16);
}
// short-family LDS stores (TBAA-compatible with s8v loads)
__device__ __forceinline__ void st8(void* p, unsigned int a, unsigned int b){
  union{ unsigned int u[2]; s4v v; } z; z.u[0]=a; z.u[1]=b;
  *(s4v*)p = z.v;
}
__device__ __forceinline__ void st16(void* p, unsigned int a, unsigned int b, unsigned int c, unsigned int d){
  union{ unsigned int u[4]; s8v v; } z; z.u[0]=a; z.u[1]=b; z.u[2]=c; z.u[3]=d;
  *(s8v*)p = z.v;
}

// XOR swizzle on 16B units within a 128B row
#define SWZ(row) (((((row)&7) ^ (((row)>>3)&7)))<<4)

// ---------------- merged setup kernel ----------------
// blocks 0..111: bf16-convert inw/w1/w2 (28672 elems); blocks 112..127: fuse out_proj∘proj (4096)
__global__ void setup_all(const float* __restrict__ inw, const float* __restrict__ w1,
                          const float* __restrict__ w2,
                          const float* __restrict__ out_w, const float* __restrict__ out_b,
                          const float* __restrict__ proj_w, const float* __restrict__ proj_b,
                          unsigned short* __restrict__ ws, unsigned short* __restrict__ wf_bf,
                          float* __restrict__ bfv){
  int bid = blockIdx.x;
  if (bid < 112){
    int i = bid*256 + threadIdx.x;
    if (i < 12288)      ws[i] = f2bf_rne(inw[i]);
    else if (i < 20480) ws[i] = f2bf_rne(w1[i-12288]);
    else                ws[i] = f2bf_rne(w2[i-20480]);
  } else {
    int i = (bid-112)*256 + threadIdx.x;
    int c = i>>6, k = i&63;
    float acc = 0.f;
    for (int m=0;m<64;m++) acc += proj_w[c*64+m]*out_w[m*64+k];
    wf_bf[i] = f2bf_rne(acc);
    if (k==0){
      float ab = proj_b[c];
      for (int m=0;m<64;m++) ab += proj_w[c*64+m]*out_b[m];
      bfv[c] = ab;
    }
  }
}

// ---------------- main: 512 threads = 8 waves; 2 windows; 4 waves per window ----------------
// Per-window 32KB: RA tn->P->tn2->mlp2out ; RB q->o->h[0:64] ; RC k->projout ; RD V^T->h[64:128]
// Thread map: pc=t&15, pr=(t>>4)&7, cb=t>>7 ; win=(pc>>3)&1, tok=pr*8+(pc&7)
// Wave map: wave w: window=w&1, tm=w>>1 (token rows 16tm..16tm+15)
// GEMM rule: mfma(X, Y): lane (g,c) reg r = dot(Xrow[4g+r], Yrow[c]); frags = elems 8g..8g+7 (+32*kk)
// XCD swizzle: bijective remap n = (bid&7)*1024 + bid>>3 — verified: FETCH_SIZE halved (R11).
// Divides replaced with v_rcp_f32 (value-only change; all memory ops/fences identical to R16).
// NOTE: phase-2 h-loop MUST stay "#pragma unroll 1" with the fences exactly as-is — full unroll
// breaks the P-write->pa-read LDS alias ordering (R10 NaN). Thread-map/barrier perturbations
// are schedule-fragile (R13/R14).
__global__ __launch_bounds__(512,4) void hat_main(
    const float* __restrict__ x,
    const float* __restrict__ n1g, const float* __restrict__ n1b,
    const float* __restrict__ inb,
    const unsigned short* __restrict__ wbf,
    const float* __restrict__ bfv,
    const float* __restrict__ n2g, const float* __restrict__ n2b,
    const float* __restrict__ b1, const float* __restrict__ b2,
    float* __restrict__ out)
{
  __shared__ __align__(16) unsigned char lds[65536];
  #define RA 0
  #define RB 8192
  #define RC 16384
  #define RD 24576

  const int t = threadIdx.x;
  const int l = t & 63;
  const int g = (l>>4)&3, c = l&15;
  const int w  = t>>6;                  // 0..7
  const int tm = w>>1;
  const int wb = (w&1)<<15;
  const int cb = t>>7;                  // 0..3 (16 channels each)
  const int pr = (t>>4)&7;
  const int pc = t&15;
  const int tok = pr*8 + (pc&7);
  const int wtb = ((pc>>3)&1)<<15;

  const int n = ((blockIdx.x & 7) << 10) | (blockIdx.x >> 3);   // XCD-chunked bijective remap
  const int ww2 = n&31, wh=(n>>5)&63, b=n>>11;
  const size_t pix = (size_t)(wh*8+pr)*512 + ww2*16 + pc;
  const float* xp = x + ((size_t)b*64 + 16*cb)*HWs + pix;

  const unsigned short* inw_bf = wbf;
  const unsigned short* w1_bf  = wbf + 12288;
  const unsigned short* w2_bf  = wbf + 20480;
  const unsigned short* wf_bf  = wbf + 28672;

  // ---------- phase 0a: coalesced load of 16 channels, LN1 partials ----------
  float xr[16];
  #pragma unroll
  for (int i=0;i<16;i++) xr[i] = xp[(size_t)i*HWs];
  {
    float s1=0.f, s2=0.f;
    #pragma unroll
    for (int i=0;i<16;i++){ s1 += xr[i]; s2 += xr[i]*xr[i]; }
    *(float2*)(lds + wtb + RD + cb*512 + tok*8) = make_float2(s1, s2);
  }
  __syncthreads();   // b1

  // ---------- phase 0b: LN1 normalize, stage tn ----------
  unsigned int xres[8];
  {
    float S=0.f, SS=0.f;
    #pragma unroll
    for (int grp=0; grp<4; grp++){
      float2 p = *(const float2*)(lds + wtb + RD + grp*512 + tok*8);
      S += p.x; SS += p.y;
    }
    float mu = S*(1.f/64.f);
    float var = SS*(1.f/64.f) - mu*mu;
    float rstd = rsqrtf(var + 1e-5f);
    float tv[16];
    #pragma unroll
    for (int i=0;i<16;i++) tv[i] = (xr[i]-mu)*rstd*n1g[16*cb+i] + n1b[16*cb+i];
    #pragma unroll
    for (int j=0;j<8;j++) xres[j] = cvtpk(xr[2*j], xr[2*j+1]);
    int sw = SWZ(tok);
    st16(lds + wtb + RA + tok*128 + ((32*cb   ) ^ sw),
         cvtpk(tv[0],tv[1]), cvtpk(tv[2],tv[3]), cvtpk(tv[4],tv[5]), cvtpk(tv[6],tv[7]));
    st16(lds + wtb + RA + tok*128 + ((32*cb+16) ^ sw),
         cvtpk(tv[8],tv[9]), cvtpk(tv[10],tv[11]), cvtpk(tv[12],tv[13]), cvtpk(tv[14],tv[15]));
  }
  __syncthreads();   // b2

  const int row_a = 16*tm + c;
  const int swa = SWZ(row_a);
  const float scale = 0.17677669529663688f; // 1/sqrt(32)

  // ---------- phase 1: QKV ----------
  s8v a0 = *(const s8v*)(lds + wb + RA + row_a*128 + ((16*g   ) ^ swa));
  s8v a1 = *(const s8v*)(lds + wb + RA + row_a*128 + ((64+16*g) ^ swa));
  #pragma unroll 1
  for (int chunk=0; chunk<2; chunk++){
    f4v acc[4] = {};
    #pragma unroll
    for (int tn=0;tn<4;tn++){
      s8v wf0 = *(const s8v*)(inw_bf + (64*chunk+16*tn+c)*64 + 8*g);
      s8v wf1 = *(const s8v*)(inw_bf + (64*chunk+16*tn+c)*64 + 32 + 8*g);
      acc[tn] = __builtin_amdgcn_mfma_f32_16x16x32_bf16(wf0, a0, acc[tn], 0,0,0);
      acc[tn] = __builtin_amdgcn_mfma_f32_16x16x32_bf16(wf1, a1, acc[tn], 0,0,0);
    }
    const int reg = (chunk==0) ? RB : RC;
    #pragma unroll
    for (int tn=0;tn<4;tn++){
      float4 b4 = *(const float4*)(inb + 64*chunk + 16*tn + 4*g);
      float v0=acc[tn][0]+b4.x, v1=acc[tn][1]+b4.y, v2=acc[tn][2]+b4.z, v3=acc[tn][3]+b4.w;
      if (chunk==0){ v0*=scale; v1*=scale; v2*=scale; v3*=scale; }
      st8(lds + wb + reg + row_a*128 + ((2*(16*tn+4*g)) ^ swa), cvtpk(v0,v1), cvtpk(v2,v3));
    }
  }
  { // V chunk (unflipped) -> transposed packed write to RD (V^T[d][tok])
    f4v acc[4] = {};
    #pragma unroll
    for (int tn=0;tn<4;tn++){
      s8v wf0 = *(const s8v*)(inw_bf + (128+16*tn+c)*64 + 8*g);
      s8v wf1 = *(const s8v*)(inw_bf + (128+16*tn+c)*64 + 32 + 8*g);
      acc[tn] = __builtin_amdgcn_mfma_f32_16x16x32_bf16(a0, wf0, acc[tn], 0,0,0);
      acc[tn] = __builtin_amdgcn_mfma_f32_16x16x32_bf16(a1, wf1, acc[tn], 0,0,0);
    }
    #pragma unroll
    for (int tn=0;tn<4;tn++){
      int drow = 16*tn + c;
      float bias = inb[128 + drow];
      st8(lds + wb + RD + drow*128 + ((2*(16*tm+4*g)) ^ SWZ(drow)),
          cvtpk(acc[tn][0]+bias, acc[tn][1]+bias), cvtpk(acc[tn][2]+bias, acc[tn][3]+bias));
    }
  }
  __syncthreads();   // b3

  // ---------- phase 2: attention ----------
  #pragma unroll 1
  for (int h=0; h<2; h++){
    s8v qa = *(const s8v*)(lds + wb + RB + row_a*128 + ((64*h+16*g) ^ swa));
    f4v sacc[4] = {};
    #pragma unroll
    for (int tn=0;tn<4;tn++){
      int kr = 16*tn + c;
      s8v kb = *(const s8v*)(lds + wb + RC + kr*128 + ((64*h+16*g) ^ SWZ(kr)));
      sacc[tn] = __builtin_amdgcn_mfma_f32_16x16x32_bf16(kb, qa, sacc[tn], 0,0,0);
    }
    // lane (g,c): sacc[tn][r] = S[ktok=16tn+4g+r][qtok=16tm+c]
    // softmax over ktok: in-lane tree(16) + shfl over g (16,32)
    float mt[4];
    #pragma unroll
    for (int tn=0;tn<4;tn++)
      mt[tn] = fmaxf(fmaxf(sacc[tn][0],sacc[tn][1]), fmaxf(sacc[tn][2],sacc[tn][3]));
    float m = fmaxf(fmaxf(mt[0],mt[1]), fmaxf(mt[2],mt[3]));
    m = fmaxf(m, __shfl_xor(m, 16));
    m = fmaxf(m, __shfl_xor(m, 32));
    float lsum = 0.f;
    float p[4][4];
    #pragma unroll
    for (int tn=0;tn<4;tn++)
      #pragma unroll
      for (int rr=0;rr<4;rr++){ float e = __expf(sacc[tn][rr]-m); p[tn][rr]=e; lsum+=e; }
    lsum += __shfl_xor(lsum, 16);
    lsum += __shfl_xor(lsum, 32);
    float inv = __builtin_amdgcn_rcpf(lsum);
    // P[qtok][ktok] packed write (own row)
    #pragma unroll
    for (int tn=0;tn<4;tn++)
      st8(lds + wb + RA + row_a*128 + ((2*(16*tn+4*g)) ^ swa),
          cvtpk(p[tn][0]*inv, p[tn][1]*inv), cvtpk(p[tn][2]*inv, p[tn][3]*inv));
    asm volatile("" ::: "memory");   // order P writes before pa reads (same-wave RAW)
    s8v pa0 = *(const s8v*)(lds + wb + RA + row_a*128 + ((16*g   ) ^ swa));
    s8v pa1 = *(const s8v*)(lds + wb + RA + row_a*128 + ((64+16*g) ^ swa));
    #pragma unroll
    for (int tnl=0; tnl<2; tnl++){
      int vr = 32*h + 16*tnl + c;
      int svr = SWZ(vr);
      s8v vb0 = *(const s8v*)(lds + wb + RD + vr*128 + ((16*g   ) ^ svr));
      s8v vb1 = *(const s8v*)(lds + wb + RD + vr*128 + ((64+16*g) ^ svr));
      f4v oc = {};
      oc = __builtin_amdgcn_mfma_f32_16x16x32_bf16(vb0, pa0, oc, 0,0,0);
      oc = __builtin_amdgcn_mfma_f32_16x16x32_bf16(vb1, pa1, oc, 0,0,0);
      st8(lds + wb + RB + row_a*128 + ((64*h + 32*tnl + 8*g) ^ swa),
          cvtpk(oc[0], oc[1]), cvtpk(oc[2], oc[3]));
    }
  }
  __syncthreads();   // b4 (all RC/RD reads done before proj overwrites RC)

  // ---------- phase 3: fused proj -> RC ----------
  {
    s8v oa0 = *(const s8v*)(lds + wb + RB + row_a*128 + ((16*g   ) ^ swa));
    s8v oa1 = *(const s8v*)(lds + wb + RB + row_a*128 + ((64+16*g) ^ swa));
    f4v acc[4] = {};
    #pragma unroll
    for (int tn=0;tn<4;tn++){
      s8v wf0 = *(const s8v*)(wf_bf + (16*tn+c)*64 + 8*g);
      s8v wf1 = *(const s8v*)(wf_bf + (16*tn+c)*64 + 32 + 8*g);
      acc[tn] = __builtin_amdgcn_mfma_f32_16x16x32_bf16(wf0, oa0, acc[tn], 0,0,0);
      acc[tn] = __builtin_amdgcn_mfma_f32_16x16x32_bf16(wf1, oa1, acc[tn], 0,0,0);
    }
    #pragma unroll
    for (int tn=0;tn<4;tn++){
      float4 b4 = *(const float4*)(bfv + 16*tn + 4*g);
      st8(lds + wb + RC + row_a*128 + ((2*(16*tn+4*g)) ^ swa),
          cvtpk(acc[tn][0]+b4.x, acc[tn][1]+b4.y), cvtpk(acc[tn][2]+b4.z, acc[tn][3]+b4.w));
    }
  }
  __syncthreads();   // b5 (-> thread map)

  // ---------- phase 4: residual + LN2 (thread map) ----------
  float row2[16];
  {
    int sw = SWZ(tok);
    uint4 A0 = *(const uint4*)(lds + wtb + RC + tok*128 + ((32*cb   ) ^ sw));
    uint4 A1 = *(const uint4*)(lds + wtb + RC + tok*128 + ((32*cb+16) ^ sw));
    unsigned int pr8[8] = {A0.x,A0.y,A0.z,A0.w,A1.x,A1.y,A1.z,A1.w};
    #pragma unroll
    for (int j=0;j<8;j++){
      row2[2*j]   = lo16(pr8[j]) + lo16(xres[j]);
      row2[2*j+1] = hi16(pr8[j]) + hi16(xres[j]);
    }
    float s1=0.f, s2=0.f;
    #pragma unroll
    for (int i=0;i<16;i++){ s1 += row2[i]; s2 += row2[i]*row2[i]; }
    *(float2*)(lds + wtb + RB + cb*512 + tok*8) = make_float2(s1, s2);
  }
  __syncthreads();   // b6
  {
    float S=0.f, SS=0.f;
    #pragma unroll
    for (int grp=0; grp<4; grp++){
      float2 p = *(const float2*)(lds + wtb + RB + grp*512 + tok*8);
      S += p.x; SS += p.y;
    }
    float mu2 = S*(1.f/64.f);
    float v2 = SS*(1.f/64.f) - mu2*mu2;
    float rstd2 = rsqrtf(v2 + 1e-5f);
    float tv[16];
    #pragma unroll
    for (int i=0;i<16;i++) tv[i] = (row2[i]-mu2)*rstd2*n2g[16*cb+i] + n2b[16*cb+i];
    int sw = SWZ(tok);
    st16(lds + wtb + RA + tok*128 + ((32*cb   ) ^ sw),
         cvtpk(tv[0],tv[1]), cvtpk(tv[2],tv[3]), cvtpk(tv[4],tv[5]), cvtpk(tv[6],tv[7]));
    st16(lds + wtb + RA + tok*128 + ((32*cb+16) ^ sw),
         cvtpk(tv[8],tv[9]), cvtpk(tv[10],tv[11]), cvtpk(tv[12],tv[13]), cvtpk(tv[14],tv[15]));
  }
  __syncthreads();   // b7 (-> wave map)

  // ---------- phase 5: MLP1 + gelu -> RB (h0), RD (h1) ----------
  {
    s8v la0 = *(const s8v*)(lds + wb + RA + row_a*128 + ((16*g   ) ^ swa));
    s8v la1 = *(const s8v*)(lds + wb + RA + row_a*128 + ((64+16*g) ^ swa));
    #pragma unroll 1
    for (int nch=0; nch<2; nch++){
      f4v acc[4] = {};
      #pragma unroll
      for (int tn=0;tn<4;tn++){
        s8v wf0 = *(const s8v*)(w1_bf + (64*nch+16*tn+c)*64 + 8*g);
        s8v wf1 = *(const s8v*)(w1_bf + (64*nch+16*tn+c)*64 + 32 + 8*g);
        acc[tn] = __builtin_amdgcn_mfma_f32_16x16x32_bf16(wf0, la0, acc[tn], 0,0,0);
        acc[tn] = __builtin_amdgcn_mfma_f32_16x16x32_bf16(wf1, la1, acc[tn], 0,0,0);
      }
      const int reg = nch ? RD : RB;
      #pragma unroll
      for (int tn=0;tn<4;tn++){
        float4 b4 = *(const float4*)(b1 + 64*nch + 16*tn + 4*g);
        float vv[4] = {acc[tn][0]+b4.x, acc[tn][1]+b4.y, acc[tn][2]+b4.z, acc[tn][3]+b4.w};
        #pragma unroll
        for (int rr=0;rr<4;rr++){
          float v = vv[rr];
          float z = v*(1.595769122f + 0.071354816f*v*v);
          vv[rr] = v * __builtin_amdgcn_rcpf(1.f + __expf(-z));
        }
        st8(lds + wb + reg + row_a*128 + ((2*(16*tn+4*g)) ^ swa), cvtpk(vv[0],vv[1]), cvtpk(vv[2],vv[3]));
      }
    }
  }
  asm volatile("" ::: "memory");   // order MLP1 h-writes before MLP2 ha reads (same-wave RAW)
  // ---------- phase 6: MLP2 -> RA (own rows; no barrier needed) ----------
  {
    f4v acc[4] = {};
    #pragma unroll
    for (int kk=0;kk<4;kk++){
      const int reg = (kk<2) ? RB : RD;
      s8v ha = *(const s8v*)(lds + wb + reg + row_a*128 + ((64*(kk&1)+16*g) ^ swa));
      #pragma unroll
      for (int tn=0;tn<4;tn++){
        s8v wf = *(const s8v*)(w2_bf + (16*tn+c)*128 + 32*kk + 8*g);
        acc[tn] = __builtin_amdgcn_mfma_f32_16x16x32_bf16(wf, ha, acc[tn], 0,0,0);
      }
    }
    #pragma unroll
    for (int tn=0;tn<4;tn++){
      float4 b4 = *(const float4*)(b2 + 16*tn + 4*g);
      st8(lds + wb + RA + row_a*128 + ((2*(16*tn+4*g)) ^ swa),
          cvtpk(acc[tn][0]+b4.x, acc[tn][1]+b4.y), cvtpk(acc[tn][2]+b4.z, acc[tn][3]+b4.w));
    }
  }
  __syncthreads();   // b8 (-> thread map)

  // ---------- epilogue: + residual (row2 regs), coalesced store ----------
  {
    int sw = SWZ(tok);
    uint4 A0 = *(const uint4*)(lds + wtb + RA + tok*128 + ((32*cb   ) ^ sw));
    uint4 A1 = *(const uint4*)(lds + wtb + RA + tok*128 + ((32*cb+16) ^ sw));
    unsigned int pr8[8] = {A0.x,A0.y,A0.z,A0.w,A1.x,A1.y,A1.z,A1.w};
    float* op = out + ((size_t)b*64 + 16*cb)*HWs + pix;
    #pragma unroll
    for (int j=0;j<8;j++){
      op[(size_t)(2*j  )*HWs] = lo16(pr8[j]) + row2[2*j];
      op[(size_t)(2*j+1)*HWs] = hi16(pr8[j]) + row2[2*j+1];
    }
  }
}

extern "C" void kernel_launch(void* const* d_in, const int* in_sizes, int n_in,
                              void* d_out, int out_size, void* d_ws, size_t ws_size,
                              hipStream_t stream) {
  const float* x    = (const float*)d_in[0];
  const float* n1g  = (const float*)d_in[1];
  const float* n1b  = (const float*)d_in[2];
  const float* inw  = (const float*)d_in[3];
  const float* inb  = (const float*)d_in[4];
  const float* outw = (const float*)d_in[5];
  const float* outb = (const float*)d_in[6];
  const float* pw   = (const float*)d_in[7];
  const float* pb   = (const float*)d_in[8];
  const float* n2g  = (const float*)d_in[9];
  const float* n2b  = (const float*)d_in[10];
  const float* w1   = (const float*)d_in[11];
  const float* b1   = (const float*)d_in[12];
  const float* w2   = (const float*)d_in[13];
  const float* b2   = (const float*)d_in[14];

  unsigned short* wsu = (unsigned short*)d_ws;
  unsigned short* wf_bf = wsu + 28672;
  float* bfv = (float*)((char*)d_ws + 65536);

  hipLaunchKernelGGL(setup_all, dim3(128), dim3(256), 0, stream,
                     inw, w1, w2, outw, outb, pw, pb, wsu, wf_bf, bfv);
  hipLaunchKernelGGL(hat_main, dim3(8192), dim3(512), 0, stream,
                     x, n1g, n1b, inb, wsu, bfv, n2g, n2b, b1, b2, (float*)d_out);
}

// Round 19
// 618.389 us; speedup vs baseline: 1.0191x; 1.0004x over previous
//
#include <hip/hip_runtime.h>
#include <math.h>

#define HWs (512*512)

typedef short  s8v __attribute__((ext_vector_type(8)));   // 8 bf16 (4 VGPRs)
typedef short  s4v __attribute__((ext_vector_type(4)));   // 4 bf16 (2 VGPRs)
typedef float  f4v __attribute__((ext_vector_type(4)));   // MFMA acc

__device__ __forceinline__ float lo16(unsigned int u){ union{unsigned int i; float f;} z; z.i=u<<16;         return z.f; }
__device__ __forceinline__ float hi16(unsigned int u){ union{unsigned int i; float f;} z; z.i=u&0xffff0000u; return z.f; }
__device__ __forceinline__ unsigned int cvtpk(float lo, float hi){
  unsigned int r; asm("v_cvt_pk_bf16_f32 %0, %1, %2" : "=v"(r) : "v"(lo), "v"(hi)); return r;
}
__device__ __forceinline__ unsigned short f2bf_rne(float f){
  union{float g; unsigned int u;} a; a.g=f;
  unsigned int r = a.u + 0x7fffu + ((a.u>>16)&1u);
  return (unsigned short)(r>>16);
}
// short-family LDS stores (TBAA-compatible with s8v loads)
__device__ __forceinline__ void st8(void* p, unsigned int a, unsigned int b){
  union{ unsigned int u[2]; s4v v; } z; z.u[0]=a; z.u[1]=b;
  *(s4v*)p = z.v;
}
__device__ __forceinline__ void st16(void* p, unsigned int a, unsigned int b, unsigned int c, unsigned int d){
  union{ unsigned int u[4]; s8v v; } z; z.u[0]=a; z.u[1]=b; z.u[2]=c; z.u[3]=d;
  *(s8v*)p = z.v;
}

// XOR swizzle on 16B units within a 128B row
#define SWZ(row) (((((row)&7) ^ (((row)>>3)&7)))<<4)

// ---------------- merged setup kernel ----------------
// blocks 0..111: bf16-convert inw/w1/w2 (28672 elems); blocks 112..127: fuse out_proj∘proj (4096)
__global__ void setup_all(const float* __restrict__ inw, const float* __restrict__ w1,
                          const float* __restrict__ w2,
                          const float* __restrict__ out_w, const float* __restrict__ out_b,
                          const float* __restrict__ proj_w, const float* __restrict__ proj_b,
                          unsigned short* __restrict__ ws, unsigned short* __restrict__ wf_bf,
                          float* __restrict__ bfv){
  int bid = blockIdx.x;
  if (bid < 112){
    int i = bid*256 + threadIdx.x;
    if (i < 12288)      ws[i] = f2bf_rne(inw[i]);
    else if (i < 20480) ws[i] = f2bf_rne(w1[i-12288]);
    else                ws[i] = f2bf_rne(w2[i-20480]);
  } else {
    int i = (bid-112)*256 + threadIdx.x;
    int c = i>>6, k = i&63;
    float acc = 0.f;
    for (int m=0;m<64;m++) acc += proj_w[c*64+m]*out_w[m*64+k];
    wf_bf[i] = f2bf_rne(acc);
    if (k==0){
      float ab = proj_b[c];
      for (int m=0;m<64;m++) ab += proj_w[c*64+m]*out_b[m];
      bfv[c] = ab;
    }
  }
}

// ---------------- main: 512 threads = 8 waves; 2 windows; 4 waves per window ----------------
// Per-window 32KB: RA tn->P->tn2->mlp2out ; RB q->o->h[0:64] ; RC k->projout ; RD V^T->h[64:128]
// Thread map: pc=t&15, pr=(t>>4)&7, cb=t>>7 ; win=(pc>>3)&1, tok=pr*8+(pc&7)
// Wave map: wave w: window=w&1, tm=w>>1 (token rows 16tm..16tm+15)
// GEMM rule: mfma(X, Y): lane (g,c) reg r = dot(Xrow[4g+r], Yrow[c]); frags = elems 8g..8g+7 (+32*kk)
// XCD swizzle: bijective remap n = (bid&7)*1024 + bid>>3 — verified: FETCH_SIZE halved (R11).
// Divides via v_rcp_f32 (value-only change; verified R17).
// NOTE: ALL phase loops MUST keep their exact unroll pragmas — every unroll change tried
// (phase-2 h-loop R10, phase-1 chunk loop R18) flipped codegen to NaN on this toolchain.
// Thread-map/barrier perturbations are likewise schedule-fragile (R13/R14). Do not touch.
__global__ __launch_bounds__(512,4) void hat_main(
    const float* __restrict__ x,
    const float* __restrict__ n1g, const float* __restrict__ n1b,
    const float* __restrict__ inb,
    const unsigned short* __restrict__ wbf,
    const float* __restrict__ bfv,
    const float* __restrict__ n2g, const float* __restrict__ n2b,
    const float* __restrict__ b1, const float* __restrict__ b2,
    float* __restrict__ out)
{
  __shared__ __align__(16) unsigned char lds[65536];
  #define RA 0
  #define RB 8192
  #define RC 16384
  #define RD 24576

  const int t = threadIdx.x;
  const int l = t & 63;
  const int g = (l>>4)&3, c = l&15;
  const int w  = t>>6;                  // 0..7
  const int tm = w>>1;
  const int wb = (w&1)<<15;
  const int cb = t>>7;                  // 0..3 (16 channels each)
  const int pr = (t>>4)&7;
  const int pc = t&15;
  const int tok = pr*8 + (pc&7);
  const int wtb = ((pc>>3)&1)<<15;

  const int n = ((blockIdx.x & 7) << 10) | (blockIdx.x >> 3);   // XCD-chunked bijective remap
  const int ww2 = n&31, wh=(n>>5)&63, b=n>>11;
  const size_t pix = (size_t)(wh*8+pr)*512 + ww2*16 + pc;
  const float* xp = x + ((size_t)b*64 + 16*cb)*HWs + pix;

  const unsigned short* inw_bf = wbf;
  const unsigned short* w1_bf  = wbf + 12288;
  const unsigned short* w2_bf  = wbf + 20480;
  const unsigned short* wf_bf  = wbf + 28672;

  // ---------- phase 0a: coalesced load of 16 channels, LN1 partials ----------
  float xr[16];
  #pragma unroll
  for (int i=0;i<16;i++) xr[i] = xp[(size_t)i*HWs];
  {
    float s1=0.f, s2=0.f;
    #pragma unroll
    for (int i=0;i<16;i++){ s1 += xr[i]; s2 += xr[i]*xr[i]; }
    *(float2*)(lds + wtb + RD + cb*512 + tok*8) = make_float2(s1, s2);
  }
  __syncthreads();   // b1

  // ---------- phase 0b: LN1 normalize, stage tn ----------
  unsigned int xres[8];
  {
    float S=0.f, SS=0.f;
    #pragma unroll
    for (int grp=0; grp<4; grp++){
      float2 p = *(const float2*)(lds + wtb + RD + grp*512 + tok*8);
      S += p.x; SS += p.y;
    }
    float mu = S*(1.f/64.f);
    float var = SS*(1.f/64.f) - mu*mu;
    float rstd = rsqrtf(var + 1e-5f);
    float tv[16];
    #pragma unroll
    for (int i=0;i<16;i++) tv[i] = (xr[i]-mu)*rstd*n1g[16*cb+i] + n1b[16*cb+i];
    #pragma unroll
    for (int j=0;j<8;j++) xres[j] = cvtpk(xr[2*j], xr[2*j+1]);
    int sw = SWZ(tok);
    st16(lds + wtb + RA + tok*128 + ((32*cb   ) ^ sw),
         cvtpk(tv[0],tv[1]), cvtpk(tv[2],tv[3]), cvtpk(tv[4],tv[5]), cvtpk(tv[6],tv[7]));
    st16(lds + wtb + RA + tok*128 + ((32*cb+16) ^ sw),
         cvtpk(tv[8],tv[9]), cvtpk(tv[10],tv[11]), cvtpk(tv[12],tv[13]), cvtpk(tv[14],tv[15]));
  }
  __syncthreads();   // b2

  const int row_a = 16*tm + c;
  const int swa = SWZ(row_a);
  const float scale = 0.17677669529663688f; // 1/sqrt(32)

  // ---------- phase 1: QKV ----------
  s8v a0 = *(const s8v*)(lds + wb + RA + row_a*128 + ((16*g   ) ^ swa));
  s8v a1 = *(const s8v*)(lds + wb + RA + row_a*128 + ((64+16*g) ^ swa));
  #pragma unroll 1
  for (int chunk=0; chunk<2; chunk++){
    f4v acc[4] = {};
    #pragma unroll
    for (int tn=0;tn<4;tn++){
      s8v wf0 = *(const s8v*)(inw_bf + (64*chunk+16*tn+c)*64 + 8*g);
      s8v wf1 = *(const s8v*)(inw_bf + (64*chunk+16*tn+c)*64 + 32 + 8*g);
      acc[tn] = __builtin_amdgcn_mfma_f32_16x16x32_bf16(wf0, a0, acc[tn], 0,0,0);
      acc[tn] = __builtin_amdgcn_mfma_f32_16x16x32_bf16(wf1, a1, acc[tn], 0,0,0);
    }
    const int reg = (chunk==0) ? RB : RC;
    #pragma unroll
    for (int tn=0;tn<4;tn++){
      float4 b4 = *(const float4*)(inb + 64*chunk + 16*tn + 4*g);
      float v0=acc[tn][0]+b4.x, v1=acc[tn][1]+b4.y, v2=acc[tn][2]+b4.z, v3=acc[tn][3]+b4.w;
      if (chunk==0){ v0*=scale; v1*=scale; v2*=scale; v3*=scale; }
      st8(lds + wb + reg + row_a*128 + ((2*(16*tn+4*g)) ^ swa), cvtpk(v0,v1), cvtpk(v2,v3));
    }
  }
  { // V chunk (unflipped) -> transposed packed write to RD (V^T[d][tok])
    f4v acc[4] = {};
    #pragma unroll
    for (int tn=0;tn<4;tn++){
      s8v wf0 = *(const s8v*)(inw_bf + (128+16*tn+c)*64 + 8*g);
      s8v wf1 = *(const s8v*)(inw_bf + (128+16*tn+c)*64 + 32 + 8*g);
      acc[tn] = __builtin_amdgcn_mfma_f32_16x16x32_bf16(a0, wf0, acc[tn], 0,0,0);
      acc[tn] = __builtin_amdgcn_mfma_f32_16x16x32_bf16(a1, wf1, acc[tn], 0,0,0);
    }
    #pragma unroll
    for (int tn=0;tn<4;tn++){
      int drow = 16*tn + c;
      float bias = inb[128 + drow];
      st8(lds + wb + RD + drow*128 + ((2*(16*tm+4*g)) ^ SWZ(drow)),
          cvtpk(acc[tn][0]+bias, acc[tn][1]+bias), cvtpk(acc[tn][2]+bias, acc[tn][3]+bias));
    }
  }
  __syncthreads();   // b3

  // ---------- phase 2: attention ----------
  #pragma unroll 1
  for (int h=0; h<2; h++){
    s8v qa = *(const s8v*)(lds + wb + RB + row_a*128 + ((64*h+16*g) ^ swa));
    f4v sacc[4] = {};
    #pragma unroll
    for (int tn=0;tn<4;tn++){
      int kr = 16*tn + c;
      s8v kb = *(const s8v*)(lds + wb + RC + kr*128 + ((64*h+16*g) ^ SWZ(kr)));
      sacc[tn] = __builtin_amdgcn_mfma_f32_16x16x32_bf16(kb, qa, sacc[tn], 0,0,0);
    }
    // lane (g,c): sacc[tn][r] = S[ktok=16tn+4g+r][qtok=16tm+c]
    // softmax over ktok: in-lane tree(16) + shfl over g (16,32)
    float mt[4];
    #pragma unroll
    for (int tn=0;tn<4;tn++)
      mt[tn] = fmaxf(fmaxf(sacc[tn][0],sacc[tn][1]), fmaxf(sacc[tn][2],sacc[tn][3]));
    float m = fmaxf(fmaxf(mt[0],mt[1]), fmaxf(mt[2],mt[3]));
    m = fmaxf(m, __shfl_xor(m, 16));
    m = fmaxf(m, __shfl_xor(m, 32));
    float lsum = 0.f;
    float p[4][4];
    #pragma unroll
    for (int tn=0;tn<4;tn++)
      #pragma unroll
      for (int rr=0;rr<4;rr++){ float e = __expf(sacc[tn][rr]-m); p[tn][rr]=e; lsum+=e; }
    lsum += __shfl_xor(lsum, 16);
    lsum += __shfl_xor(lsum, 32);
    float inv = __builtin_amdgcn_rcpf(lsum);
    // P[qtok][ktok] packed write (own row)
    #pragma unroll
    for (int tn=0;tn<4;tn++)
      st8(lds + wb + RA + row_a*128 + ((2*(16*tn+4*g)) ^ swa),
          cvtpk(p[tn][0]*inv, p[tn][1]*inv), cvtpk(p[tn][2]*inv, p[tn][3]*inv));
    asm volatile("" ::: "memory");   // order P writes before pa reads (same-wave RAW)
    s8v pa0 = *(const s8v*)(lds + wb + RA + row_a*128 + ((16*g   ) ^ swa));
    s8v pa1 = *(const s8v*)(lds + wb + RA + row_a*128 + ((64+16*g) ^ swa));
    #pragma unroll
    for (int tnl=0; tnl<2; tnl++){
      int vr = 32*h + 16*tnl + c;
      int svr = SWZ(vr);
      s8v vb0 = *(const s8v*)(lds + wb + RD + vr*128 + ((16*g   ) ^ svr));
      s8v vb1 = *(const s8v*)(lds + wb + RD + vr*128 + ((64+16*g) ^ svr));
      f4v oc = {};
      oc = __builtin_amdgcn_mfma_f32_16x16x32_bf16(vb0, pa0, oc, 0,0,0);
      oc = __builtin_amdgcn_mfma_f32_16x16x32_bf16(vb1, pa1, oc, 0,0,0);
      st8(lds + wb + RB + row_a*128 + ((64*h + 32*tnl + 8*g) ^ swa),
          cvtpk(oc[0], oc[1]), cvtpk(oc[2], oc[3]));
    }
  }
  __syncthreads();   // b4 (all RC/RD reads done before proj overwrites RC)

  // ---------- phase 3: fused proj -> RC ----------
  {
    s8v oa0 = *(const s8v*)(lds + wb + RB + row_a*128 + ((16*g   ) ^ swa));
    s8v oa1 = *(const s8v*)(lds + wb + RB + row_a*128 + ((64+16*g) ^ swa));
    f4v acc[4] = {};
    #pragma unroll
    for (int tn=0;tn<4;tn++){
      s8v wf0 = *(const s8v*)(wf_bf + (16*tn+c)*64 + 8*g);
      s8v wf1 = *(const s8v*)(wf_bf + (16*tn+c)*64 + 32 + 8*g);
      acc[tn] = __builtin_amdgcn_mfma_f32_16x16x32_bf16(wf0, oa0, acc[tn], 0,0,0);
      acc[tn] = __builtin_amdgcn_mfma_f32_16x16x32_bf16(wf1, oa1, acc[tn], 0,0,0);
    }
    #pragma unroll
    for (int tn=0;tn<4;tn++){
      float4 b4 = *(const float4*)(bfv + 16*tn + 4*g);
      st8(lds + wb + RC + row_a*128 + ((2*(16*tn+4*g)) ^ swa),
          cvtpk(acc[tn][0]+b4.x, acc[tn][1]+b4.y), cvtpk(acc[tn][2]+b4.z, acc[tn][3]+b4.w));
    }
  }
  __syncthreads();   // b5 (-> thread map)

  // ---------- phase 4: residual + LN2 (thread map) ----------
  float row2[16];
  {
    int sw = SWZ(tok);
    uint4 A0 = *(const uint4*)(lds + wtb + RC + tok*128 + ((32*cb   ) ^ sw));
    uint4 A1 = *(const uint4*)(lds + wtb + RC + tok*128 + ((32*cb+16) ^ sw));
    unsigned int pr8[8] = {A0.x,A0.y,A0.z,A0.w,A1.x,A1.y,A1.z,A1.w};
    #pragma unroll
    for (int j=0;j<8;j++){
      row2[2*j]   = lo16(pr8[j]) + lo16(xres[j]);
      row2[2*j+1] = hi16(pr8[j]) + hi16(xres[j]);
    }
    float s1=0.f, s2=0.f;
    #pragma unroll
    for (int i=0;i<16;i++){ s1 += row2[i]; s2 += row2[i]*row2[i]; }
    *(float2*)(lds + wtb + RB + cb*512 + tok*8) = make_float2(s1, s2);
  }
  __syncthreads();   // b6
  {
    float S=0.f, SS=0.f;
    #pragma unroll
    for (int grp=0; grp<4; grp++){
      float2 p = *(const float2*)(lds + wtb + RB + grp*512 + tok*8);
      S += p.x; SS += p.y;
    }
    float mu2 = S*(1.f/64.f);
    float v2 = SS*(1.f/64.f) - mu2*mu2;
    float rstd2 = rsqrtf(v2 + 1e-5f);
    float tv[16];
    #pragma unroll
    for (int i=0;i<16;i++) tv[i] = (row2[i]-mu2)*rstd2*n2g[16*cb+i] + n2b[16*cb+i];
    int sw = SWZ(tok);
    st16(lds + wtb + RA + tok*128 + ((32*cb   ) ^ sw),
         cvtpk(tv[0],tv[1]), cvtpk(tv[2],tv[3]), cvtpk(tv[4],tv[5]), cvtpk(tv[6],tv[7]));
    st16(lds + wtb + RA + tok*128 + ((32*cb+16) ^ sw),
         cvtpk(tv[8],tv[9]), cvtpk(tv[10],tv[11]), cvtpk(tv[12],tv[13]), cvtpk(tv[14],tv[15]));
  }
  __syncthreads();   // b7 (-> wave map)

  // ---------- phase 5: MLP1 + gelu -> RB (h0), RD (h1) ----------
  {
    s8v la0 = *(const s8v*)(lds + wb + RA + row_a*128 + ((16*g   ) ^ swa));
    s8v la1 = *(const s8v*)(lds + wb + RA + row_a*128 + ((64+16*g) ^ swa));
    #pragma unroll 1
    for (int nch=0; nch<2; nch++){
      f4v acc[4] = {};
      #pragma unroll
      for (int tn=0;tn<4;tn++){
        s8v wf0 = *(const s8v*)(w1_bf + (64*nch+16*tn+c)*64 + 8*g);
        s8v wf1 = *(const s8v*)(w1_bf + (64*nch+16*tn+c)*64 + 32 + 8*g);
        acc[tn] = __builtin_amdgcn_mfma_f32_16x16x32_bf16(wf0, la0, acc[tn], 0,0,0);
        acc[tn] = __builtin_amdgcn_mfma_f32_16x16x32_bf16(wf1, la1, acc[tn], 0,0,0);
      }
      const int reg = nch ? RD : RB;
      #pragma unroll
      for (int tn=0;tn<4;tn++){
        float4 b4 = *(const float4*)(b1 + 64*nch + 16*tn + 4*g);
        float vv[4] = {acc[tn][0]+b4.x, acc[tn][1]+b4.y, acc[tn][2]+b4.z, acc[tn][3]+b4.w};
        #pragma unroll
        for (int rr=0;rr<4;rr++){
          float v = vv[rr];
          float z = v*(1.595769122f + 0.071354816f*v*v);
          vv[rr] = v * __builtin_amdgcn_rcpf(1.f + __expf(-z));
        }
        st8(lds + wb + reg + row_a*128 + ((2*(16*tn+4*g)) ^ swa), cvtpk(vv[0],vv[1]), cvtpk(vv[2],vv[3]));
      }
    }
  }
  asm volatile("" ::: "memory");   // order MLP1 h-writes before MLP2 ha reads (same-wave RAW)
  // ---------- phase 6: MLP2 -> RA (own rows; no barrier needed) ----------
  {
    f4v acc[4] = {};
    #pragma unroll
    for (int kk=0;kk<4;kk++){
      const int reg = (kk<2) ? RB : RD;
      s8v ha = *(const s8v*)(lds + wb + reg + row_a*128 + ((64*(kk&1)+16*g) ^ swa));
      #pragma unroll
      for (int tn=0;tn<4;tn++){
        s8v wf = *(const s8v*)(w2_bf + (16*tn+c)*128 + 32*kk + 8*g);
        acc[tn] = __builtin_amdgcn_mfma_f32_16x16x32_bf16(wf, ha, acc[tn], 0,0,0);
      }
    }
    #pragma unroll
    for (int tn=0;tn<4;tn++){
      float4 b4 = *(const float4*)(b2 + 16*tn + 4*g);
      st8(lds + wb + RA + row_a*128 + ((2*(16*tn+4*g)) ^ swa),
          cvtpk(acc[tn][0]+b4.x, acc[tn][1]+b4.y), cvtpk(acc[tn][2]+b4.z, acc[tn][3]+b4.w));
    }
  }
  __syncthreads();   // b8 (-> thread map)

  // ---------- epilogue: + residual (row2 regs), coalesced store ----------
  {
    int sw = SWZ(tok);
    uint4 A0 = *(const uint4*)(lds + wtb + RA + tok*128 + ((32*cb   ) ^ sw));
    uint4 A1 = *(const uint4*)(lds + wtb + RA + tok*128 + ((32*cb+16) ^ sw));
    unsigned int pr8[8] = {A0.x,A0.y,A0.z,A0.w,A1.x,A1.y,A1.z,A1.w};
    float* op = out + ((size_t)b*64 + 16*cb)*HWs + pix;
    #pragma unroll
    for (int j=0;j<8;j++){
      op[(size_t)(2*j  )*HWs] = lo16(pr8[j]) + row2[2*j];
      op[(size_t)(2*j+1)*HWs] = hi16(pr8[j]) + row2[2*j+1];
    }
  }
}

extern "C" void kernel_launch(void* const* d_in, const int* in_sizes, int n_in,
                              void* d_out, int out_size, void* d_ws, size_t ws_size,
                              hipStream_t stream) {
  const float* x    = (const float*)d_in[0];
  const float* n1g  = (const float*)d_in[1];
  const float* n1b  = (const float*)d_in[2];
  const float* inw  = (const float*)d_in[3];
  const float* inb  = (const float*)d_in[4];
  const float* outw = (const float*)d_in[5];
  const float* outb = (const float*)d_in[6];
  const float* pw   = (const float*)d_in[7];
  const float* pb   = (const float*)d_in[8];
  const float* n2g  = (const float*)d_in[9];
  const float* n2b  = (const float*)d_in[10];
  const float* w1   = (const float*)d_in[11];
  const float* b1   = (const float*)d_in[12];
  const float* w2   = (const float*)d_in[13];
  const float* b2   = (const float*)d_in[14];

  unsigned short* wsu = (unsigned short*)d_ws;
  unsigned short* wf_bf = wsu + 28672;
  float* bfv = (float*)((char*)d_ws + 65536);

  hipLaunchKernelGGL(setup_all, dim3(128), dim3(256), 0, stream,
                     inw, w1, w2, outw, outb, pw, pb, wsu, wf_bf, bfv);
  hipLaunchKernelGGL(hat_main, dim3(8192), dim3(512), 0, stream,
                     x, n1g, n1b, inb, wsu, bfv, n2g, n2b, b1, b2, (float*)d_out);
}